// Round 3
// baseline (273.308 us; speedup 1.0000x reference)
//
#include <hip/hip_runtime.h>
#include <math.h>

typedef unsigned int u32;
typedef __attribute__((ext_vector_type(4))) unsigned int uint4v;

// out[r][c] = h[r][c] * S[c][c], S diagonal +-1 (fp32) => XOR of fp32 sign bit.
//
// v4: split NT hints. Evidence: R0 (NT both) apply <79us, R1 (NT both,
// scatter) 86us, R2 (plain both) 95us. Mechanism: graph replay re-reads h
// (134 MB, fits 256 MB L3) every iteration; plain stores allocate the dead
// output stream in L2/L3 and evict h (134+134 > 256 MB). R1's FETCH=66MB
// (< h's 134MB) proves partial L3 retention under NT stores.
// => plain cached LOADS (retain h in L3) + NT STORES (bypass, don't evict).
// Two-kernel structure: 16KB mask table in ws (R1 proved in-kernel diagonal
// scatter costs ~8us vs ~2-3us for the extra launch).

__global__ __launch_bounds__(256) void parity_mask_kernel(
    const u32* __restrict__ S, u32* __restrict__ mask, int dim)
{
    const int c = blockIdx.x * blockDim.x + threadIdx.x;
    if (c < dim) mask[c] = S[(long long)c * dim + c] & 0x80000000u;
}

__global__ __launch_bounds__(256) void parity_apply_kernel(
    const uint4v* __restrict__ hv,
    const uint4v* __restrict__ maskv,   // dim/4 sign-mask chunks (16 KB, L2-hit)
    uint4v* __restrict__ ov,
    int cpr,                            // chunks per row = dim/4
    long long n_chunks)
{
    const long long tid = (long long)blockIdx.x * blockDim.x + threadIdx.x;
    const long long s   = (long long)gridDim.x * blockDim.x;

    if ((s % cpr) == 0 && tid + 7 * s < n_chunks) {
        // Fixed column group for this thread across all 8 chunks:
        // one coalesced 16B mask load, then 8x {cached load, xor, NT store}.
        const uint4v m = maskv[(int)(tid % cpr)];
        uint4v v[8];
#pragma unroll
        for (int k = 0; k < 8; ++k)
            v[k] = hv[tid + k * s];          // plain cached load (L3-retain h)
#pragma unroll
        for (int k = 0; k < 8; ++k) v[k] ^= m;
#pragma unroll
        for (int k = 0; k < 8; ++k)
            __builtin_nontemporal_store(v[k], &ov[tid + k * s]);  // bypass L3
    } else {
        for (long long i = tid; i < n_chunks; i += s) {
            uint4v m = maskv[(int)(i % cpr)];
            uint4v v = hv[i];
            v ^= m;
            __builtin_nontemporal_store(v, &ov[i]);
        }
    }
}

// Fallback (ws too small): read S's diagonal directly.
__global__ __launch_bounds__(256) void parity_fallback_kernel(
    const u32* __restrict__ h, const u32* __restrict__ S, u32* __restrict__ out,
    int dim, long long n_chunks)
{
    const int cpr = dim >> 2;
    const long long tid    = (long long)blockIdx.x * blockDim.x + threadIdx.x;
    const long long stride = (long long)gridDim.x * blockDim.x;
    const uint4v* hv = (const uint4v*)h;
    uint4v* ov = (uint4v*)out;
    for (long long i = tid; i < n_chunks; i += stride) {
        const int c0 = (int)(i % cpr) * 4;
        uint4v v = hv[i];
#pragma unroll
        for (int j = 0; j < 4; ++j) {
            const long long c = c0 + j;
            v[j] ^= (S[c * (long long)dim + c] & 0x80000000u);
        }
        __builtin_nontemporal_store(v, &ov[i]);
    }
}

extern "C" void kernel_launch(void* const* d_in, const int* in_sizes, int n_in,
                              void* d_out, int out_size, void* d_ws, size_t ws_size,
                              hipStream_t stream) {
    (void)n_in; (void)out_size;
    const u32* h = (const u32*)d_in[0];
    const u32* S = (const u32*)d_in[1];
    u32* out = (u32*)d_out;

    const long long s_elems = (long long)in_sizes[1];
    const int dim = (int)llroundl(sqrtl((long double)s_elems));  // 4096
    const long long n = (long long)in_sizes[0];
    const long long n_chunks = n >> 2;        // 4 fp32 per 16B chunk
    const int cpr = dim >> 2;                 // 1024

    const int block = 256;
    if (ws_size >= (size_t)dim * sizeof(u32) && (dim & 3) == 0) {
        u32* mask = (u32*)d_ws;
        parity_mask_kernel<<<(dim + block - 1) / block, block, 0, stream>>>(
            S, mask, dim);
        // 8 chunks/thread: grid = ceil(n_chunks / (block*8)).
        // 8192x4096: 4096 blocks; stride = 1,048,576 = 1024*1024 -> fast path.
        long long grid = (n_chunks + (long long)block * 8 - 1) / ((long long)block * 8);
        if (grid < 1) grid = 1;
        parity_apply_kernel<<<(int)grid, block, 0, stream>>>(
            (const uint4v*)h, (const uint4v*)mask, (uint4v*)out, cpr, n_chunks);
    } else {
        int grid = 2048;
        if ((long long)grid * block > n_chunks) {
            grid = (int)((n_chunks + block - 1) / block);
            if (grid < 1) grid = 1;
        }
        parity_fallback_kernel<<<grid, block, 0, stream>>>(h, S, out, dim, n_chunks);
    }
}

// Round 4
// 249.595 us; speedup vs baseline: 1.0950x; 1.0950x over previous
//
#include <hip/hip_runtime.h>
#include <math.h>

typedef unsigned int u32;
typedef __attribute__((ext_vector_type(4))) unsigned int uint4v;

// out[r][c] = h[r][c] * S[c][c], S diagonal +-1 (fp32) => XOR of fp32 sign bit.
//
// v5: wave-contiguous batching. Empirical ranking (per-dispatch):
//   R0 NT/NT+table <79us | R1 NT/NT+scatter 86 | R2 plain/plain 95 | R3 plain/NT 105
// => NT on LOADS is the key hint (request-path/no-allocate, not bytes:
// FETCH identical 66MB in R1/R3 yet 20% faster with NT). Keep NT-NT + table.
// Remaining suspect vs the 6.3-6.7 TB/s fill/copy ceiling: R0's 8 chunks
// per thread at 16 MiB stride -> ~80k live 1KB bursts chip-wide -> DRAM
// row thrash. v5 changes ONE variable vs R0: k-stride 16MiB -> 1KB, so each
// wave covers one contiguous 8KB read + 8KB write region.

__global__ __launch_bounds__(256) void parity_mask_kernel(
    const u32* __restrict__ S, u32* __restrict__ mask, int dim)
{
    const int c = blockIdx.x * blockDim.x + threadIdx.x;
    if (c < dim) mask[c] = S[(long long)c * dim + c] & 0x80000000u;
}

// Fast path: requires n_chunks == gridDim.x*2048 and cpr % 512 == 0.
// Wave w of block b owns chunks [b*2048 + w*512, +512): contiguous 8 KB.
// chunk(k) = base_w + lane + 64k; col-chunk = (base_w % cpr) + lane + 64k,
// which never wraps because the wave span (512) divides cpr.
__global__ __launch_bounds__(256) void parity_apply_contig(
    const uint4v* __restrict__ hv,
    const uint4v* __restrict__ maskv,   // cpr sign-mask chunks (16 KB, L2-hit)
    uint4v* __restrict__ ov,
    int cpr)
{
    const int t    = threadIdx.x;
    const int lane = t & 63;
    const int wv   = t >> 6;
    const long long base_w = (long long)blockIdx.x * 2048 + (long long)wv * 512;
    const int mb = (int)(base_w % cpr);

    uint4v m[8], v[8];
#pragma unroll
    for (int k = 0; k < 8; ++k)
        m[k] = maskv[mb + lane + 64 * k];            // coalesced, L2-hit
#pragma unroll
    for (int k = 0; k < 8; ++k)
        v[k] = __builtin_nontemporal_load(&hv[base_w + lane + 64 * k]);
#pragma unroll
    for (int k = 0; k < 8; ++k) v[k] ^= m[k];
#pragma unroll
    for (int k = 0; k < 8; ++k)
        __builtin_nontemporal_store(v[k], &ov[base_w + lane + 64 * k]);
}

// Generic path (R0's apply): strided batch-8 fast lane + grid-stride tail.
__global__ __launch_bounds__(256) void parity_apply_kernel(
    const uint4v* __restrict__ hv,
    const uint4v* __restrict__ maskv,
    uint4v* __restrict__ ov,
    int cpr,
    long long n_chunks)
{
    const long long tid = (long long)blockIdx.x * blockDim.x + threadIdx.x;
    const long long s   = (long long)gridDim.x * blockDim.x;

    if ((s % cpr) == 0 && tid + 7 * s < n_chunks) {
        const uint4v m = maskv[(int)(tid % cpr)];
        uint4v v[8];
#pragma unroll
        for (int k = 0; k < 8; ++k)
            v[k] = __builtin_nontemporal_load(&hv[tid + k * s]);
#pragma unroll
        for (int k = 0; k < 8; ++k) v[k] ^= m;
#pragma unroll
        for (int k = 0; k < 8; ++k)
            __builtin_nontemporal_store(v[k], &ov[tid + k * s]);
    } else {
        for (long long i = tid; i < n_chunks; i += s) {
            uint4v m = maskv[(int)(i % cpr)];
            uint4v v = __builtin_nontemporal_load(&hv[i]);
            v ^= m;
            __builtin_nontemporal_store(v, &ov[i]);
        }
    }
}

// Fallback (ws too small): read S's diagonal directly.
__global__ __launch_bounds__(256) void parity_fallback_kernel(
    const u32* __restrict__ h, const u32* __restrict__ S, u32* __restrict__ out,
    int dim, long long n_chunks)
{
    const int cpr = dim >> 2;
    const long long tid    = (long long)blockIdx.x * blockDim.x + threadIdx.x;
    const long long stride = (long long)gridDim.x * blockDim.x;
    const uint4v* hv = (const uint4v*)h;
    uint4v* ov = (uint4v*)out;
    for (long long i = tid; i < n_chunks; i += stride) {
        const int c0 = (int)(i % cpr) * 4;
        uint4v v = hv[i];
#pragma unroll
        for (int j = 0; j < 4; ++j) {
            const long long c = c0 + j;
            v[j] ^= (S[c * (long long)dim + c] & 0x80000000u);
        }
        __builtin_nontemporal_store(v, &ov[i]);
    }
}

extern "C" void kernel_launch(void* const* d_in, const int* in_sizes, int n_in,
                              void* d_out, int out_size, void* d_ws, size_t ws_size,
                              hipStream_t stream) {
    (void)n_in; (void)out_size;
    const u32* h = (const u32*)d_in[0];
    const u32* S = (const u32*)d_in[1];
    u32* out = (u32*)d_out;

    const long long s_elems = (long long)in_sizes[1];
    const int dim = (int)llroundl(sqrtl((long double)s_elems));  // 4096
    const long long n = (long long)in_sizes[0];
    const long long n_chunks = n >> 2;        // 4 fp32 per 16B chunk
    const int cpr = dim >> 2;                 // 1024

    const int block = 256;
    if (ws_size >= (size_t)dim * sizeof(u32) && (dim & 3) == 0) {
        u32* mask = (u32*)d_ws;
        parity_mask_kernel<<<(dim + block - 1) / block, block, 0, stream>>>(
            S, mask, dim);

        // Contiguous fast path: 2048 chunks (32 KB) per block.
        // 8192x4096: n_chunks = 8,388,608 -> grid = 4096, cpr = 1024 (%512==0).
        if ((cpr % 512) == 0 && (n_chunks % 2048) == 0 &&
            (n_chunks / 2048) <= 0x7fffffffLL) {
            const long long grid = n_chunks / 2048;
            parity_apply_contig<<<(int)grid, block, 0, stream>>>(
                (const uint4v*)h, (const uint4v*)mask, (uint4v*)out, cpr);
        } else {
            long long grid = (n_chunks + (long long)block * 8 - 1) /
                             ((long long)block * 8);
            if (grid < 1) grid = 1;
            parity_apply_kernel<<<(int)grid, block, 0, stream>>>(
                (const uint4v*)h, (const uint4v*)mask, (uint4v*)out, cpr, n_chunks);
        }
    } else {
        int grid = 2048;
        if ((long long)grid * block > n_chunks) {
            grid = (int)((n_chunks + block - 1) / block);
            if (grid < 1) grid = 1;
        }
        parity_fallback_kernel<<<grid, block, 0, stream>>>(h, S, out, dim, n_chunks);
    }
}

// Round 5
// 248.576 us; speedup vs baseline: 1.0995x; 1.0041x over previous
//
#include <hip/hip_runtime.h>
#include <math.h>

typedef unsigned int u32;
typedef __attribute__((ext_vector_type(4))) unsigned int uint4v;

// out[r][c] = h[r][c] * S[c][c], S diagonal +-1 (fp32) => XOR of fp32 sign bit.
//
// v6: deepen read MLP. Evidence ladder: R0 NT/NT strided <79us; R2 plain
// 95; R3 plain/NT 105; v5 NT/NT wave-contiguous ~67us (total 258.9->249.6).
// Stream locality fixed; remaining gap vs the 6.3-6.7 TB/s fill/copy
// ceiling is ~2x. Fill counters show writes saturate at 9.5% occupancy =>
// reads are the MLP-hungry side. Single variable vs v5: batch 8 -> 16
// chunks/thread (wave = 16KB contiguous = one full row at dim=4096).
// Phase 2 (mask XOR + store) is separated so live VGPRs stay ~80.

__global__ __launch_bounds__(256) void parity_mask_kernel(
    const u32* __restrict__ S, u32* __restrict__ mask, int dim)
{
    const int c = blockIdx.x * blockDim.x + threadIdx.x;
    if (c < dim) mask[c] = S[(long long)c * dim + c] & 0x80000000u;
}

// Fast path 16-deep: requires cpr % 1024 == 0 and n_chunks % 4096 == 0.
// Wave w of block b owns chunks [b*4096 + w*1024, +1024): contiguous 16 KB.
// Column chunk of (base_w + lane + 64k) is (lane + 64k) since base_w % cpr == 0.
__global__ __launch_bounds__(256) void parity_apply_contig16(
    const uint4v* __restrict__ hv,
    const uint4v* __restrict__ maskv,   // cpr sign-mask chunks (16 KB, L2-hit)
    uint4v* __restrict__ ov,
    int cpr)
{
    const int t    = threadIdx.x;
    const int lane = t & 63;
    const int wv   = t >> 6;
    const long long base_w = (long long)blockIdx.x * 4096 + (long long)wv * 1024;
    const int mb = (int)(base_w % cpr);   // 0 when cpr == 1024

    uint4v v[16];
#pragma unroll
    for (int k = 0; k < 16; ++k)
        v[k] = __builtin_nontemporal_load(&hv[base_w + lane + 64 * k]);
#pragma unroll
    for (int k = 0; k < 16; ++k) {
        const uint4v m = maskv[mb + lane + 64 * k];  // coalesced, L2-hit
        __builtin_nontemporal_store(v[k] ^ m, &ov[base_w + lane + 64 * k]);
    }
}

// Fast path 8-deep (v5, proven ~67us): cpr % 512 == 0, n_chunks % 2048 == 0.
__global__ __launch_bounds__(256) void parity_apply_contig(
    const uint4v* __restrict__ hv,
    const uint4v* __restrict__ maskv,
    uint4v* __restrict__ ov,
    int cpr)
{
    const int t    = threadIdx.x;
    const int lane = t & 63;
    const int wv   = t >> 6;
    const long long base_w = (long long)blockIdx.x * 2048 + (long long)wv * 512;
    const int mb = (int)(base_w % cpr);

    uint4v m[8], v[8];
#pragma unroll
    for (int k = 0; k < 8; ++k)
        m[k] = maskv[mb + lane + 64 * k];
#pragma unroll
    for (int k = 0; k < 8; ++k)
        v[k] = __builtin_nontemporal_load(&hv[base_w + lane + 64 * k]);
#pragma unroll
    for (int k = 0; k < 8; ++k) v[k] ^= m[k];
#pragma unroll
    for (int k = 0; k < 8; ++k)
        __builtin_nontemporal_store(v[k], &ov[base_w + lane + 64 * k]);
}

// Generic path: strided batch-8 fast lane + grid-stride tail.
__global__ __launch_bounds__(256) void parity_apply_kernel(
    const uint4v* __restrict__ hv,
    const uint4v* __restrict__ maskv,
    uint4v* __restrict__ ov,
    int cpr,
    long long n_chunks)
{
    const long long tid = (long long)blockIdx.x * blockDim.x + threadIdx.x;
    const long long s   = (long long)gridDim.x * blockDim.x;

    if ((s % cpr) == 0 && tid + 7 * s < n_chunks) {
        const uint4v m = maskv[(int)(tid % cpr)];
        uint4v v[8];
#pragma unroll
        for (int k = 0; k < 8; ++k)
            v[k] = __builtin_nontemporal_load(&hv[tid + k * s]);
#pragma unroll
        for (int k = 0; k < 8; ++k) v[k] ^= m;
#pragma unroll
        for (int k = 0; k < 8; ++k)
            __builtin_nontemporal_store(v[k], &ov[tid + k * s]);
    } else {
        for (long long i = tid; i < n_chunks; i += s) {
            uint4v m = maskv[(int)(i % cpr)];
            uint4v v = __builtin_nontemporal_load(&hv[i]);
            v ^= m;
            __builtin_nontemporal_store(v, &ov[i]);
        }
    }
}

// Fallback (ws too small): read S's diagonal directly.
__global__ __launch_bounds__(256) void parity_fallback_kernel(
    const u32* __restrict__ h, const u32* __restrict__ S, u32* __restrict__ out,
    int dim, long long n_chunks)
{
    const int cpr = dim >> 2;
    const long long tid    = (long long)blockIdx.x * blockDim.x + threadIdx.x;
    const long long stride = (long long)gridDim.x * blockDim.x;
    const uint4v* hv = (const uint4v*)h;
    uint4v* ov = (uint4v*)out;
    for (long long i = tid; i < n_chunks; i += stride) {
        const int c0 = (int)(i % cpr) * 4;
        uint4v v = hv[i];
#pragma unroll
        for (int j = 0; j < 4; ++j) {
            const long long c = c0 + j;
            v[j] ^= (S[c * (long long)dim + c] & 0x80000000u);
        }
        __builtin_nontemporal_store(v, &ov[i]);
    }
}

extern "C" void kernel_launch(void* const* d_in, const int* in_sizes, int n_in,
                              void* d_out, int out_size, void* d_ws, size_t ws_size,
                              hipStream_t stream) {
    (void)n_in; (void)out_size;
    const u32* h = (const u32*)d_in[0];
    const u32* S = (const u32*)d_in[1];
    u32* out = (u32*)d_out;

    const long long s_elems = (long long)in_sizes[1];
    const int dim = (int)llroundl(sqrtl((long double)s_elems));  // 4096
    const long long n = (long long)in_sizes[0];
    const long long n_chunks = n >> 2;        // 4 fp32 per 16B chunk
    const int cpr = dim >> 2;                 // 1024

    const int block = 256;
    if (ws_size >= (size_t)dim * sizeof(u32) && (dim & 3) == 0) {
        u32* mask = (u32*)d_ws;
        parity_mask_kernel<<<(dim + block - 1) / block, block, 0, stream>>>(
            S, mask, dim);

        if ((cpr % 1024) == 0 && (n_chunks % 4096) == 0 &&
            (n_chunks / 4096) <= 0x7fffffffLL) {
            // 16-deep: 4096 chunks (64 KB) per block. 8192x4096: grid = 2048.
            const long long grid = n_chunks / 4096;
            parity_apply_contig16<<<(int)grid, block, 0, stream>>>(
                (const uint4v*)h, (const uint4v*)mask, (uint4v*)out, cpr);
        } else if ((cpr % 512) == 0 && (n_chunks % 2048) == 0 &&
                   (n_chunks / 2048) <= 0x7fffffffLL) {
            // 8-deep (v5): 2048 chunks (32 KB) per block.
            const long long grid = n_chunks / 2048;
            parity_apply_contig<<<(int)grid, block, 0, stream>>>(
                (const uint4v*)h, (const uint4v*)mask, (uint4v*)out, cpr);
        } else {
            long long grid = (n_chunks + (long long)block * 8 - 1) /
                             ((long long)block * 8);
            if (grid < 1) grid = 1;
            parity_apply_kernel<<<(int)grid, block, 0, stream>>>(
                (const uint4v*)h, (const uint4v*)mask, (uint4v*)out, cpr, n_chunks);
        }
    } else {
        int grid = 2048;
        if ((long long)grid * block > n_chunks) {
            grid = (int)((n_chunks + block - 1) / block);
            if (grid < 1) grid = 1;
        }
        parity_fallback_kernel<<<grid, block, 0, stream>>>(h, S, out, dim, n_chunks);
    }
}